// Round 1
// baseline (8664.426 us; speedup 1.0000x reference)
//
#include <hip/hip_runtime.h>
#include <math.h>

// Problem constants
#define DD   256      // word_embd_size
#define TTT  512      // T
#define JJJ  128      // J
#define BBB  32       // B
#define NC   1536     // 6*D combined gate columns (fwd 0..767, bwd 768..1535)
#define ROWS_SRC 16384
#define ROWS_ALL 36864

// ---------------------------------------------------------------------------
// K0: prep — build token table, transposed weights (k-major), concat biases
// ---------------------------------------------------------------------------
__global__ __launch_bounds__(256) void prep_kernel(
    const int* __restrict__ cmnt, const int* __restrict__ src_tok, const int* __restrict__ tgt_tok,
    const float* __restrict__ wih_f, const float* __restrict__ wih_b,
    const float* __restrict__ whh_f, const float* __restrict__ whh_b,
    const float* __restrict__ bih_f, const float* __restrict__ bih_b,
    const float* __restrict__ bhh_f, const float* __restrict__ bhh_b,
    int* __restrict__ tok_all, float* __restrict__ wihT, float* __restrict__ whhT,
    float* __restrict__ bihc, float* __restrict__ bhhc)
{
    const int idx = blockIdx.x * blockDim.x + threadIdx.x;
    const int stride = gridDim.x * blockDim.x;
    for (int i = idx; i < ROWS_ALL; i += stride)
        tok_all[i] = (i < 16384) ? src_tok[i] : (i < 32768) ? tgt_tok[i - 16384] : cmnt[i - 32768];
    for (int i = idx; i < 256 * NC; i += stride) {
        const int k = i / NC, c = i % NC;
        wihT[i] = (c < 768) ? wih_f[(size_t)c * 256 + k] : wih_b[(size_t)(c - 768) * 256 + k];
        whhT[i] = (c < 768) ? whh_f[(size_t)c * 256 + k] : whh_b[(size_t)(c - 768) * 256 + k];
    }
    for (int i = idx; i < NC; i += stride) {
        bihc[i] = (i < 768) ? bih_f[i] : bih_b[i - 768];
        bhhc[i] = (i < 768) ? bhh_f[i] : bhh_b[i - 768];
    }
}

// ---------------------------------------------------------------------------
// K1: gi GEMM — gi[row][c] = sum_k emb[tok[row]][k] * wihT[k][c] + bihc[c]
// Tiles: BM=128, BN=64, BK=16; 256 threads; 8x4 micro-tile
// ---------------------------------------------------------------------------
__global__ __launch_bounds__(256) void gi_gemm(
    const int* __restrict__ tok, int nrows,
    const float* __restrict__ emb, const float* __restrict__ wihT,
    const float* __restrict__ bihc, float* __restrict__ gi)
{
    __shared__ __align__(16) float As[16][132];
    __shared__ __align__(16) float Bs[16][68];
    const int tid = threadIdx.x;
    const int m0 = blockIdx.x * 128;
    const int n0 = blockIdx.y * 64;

    const int ar = tid >> 2;            // 0..63
    const int ak = (tid & 3) << 2;      // 0,4,8,12
    const float* arow0 = emb + (size_t)tok[m0 + ar] * 256 + ak;
    const float* arow1 = emb + (size_t)tok[m0 + ar + 64] * 256 + ak;
    const int bk = tid >> 4;            // 0..15
    const int bn = (tid & 15) << 2;     // 0..60
    const float* bptr = wihT + (size_t)bk * NC + n0 + bn;

    const int ty = tid >> 4;            // m = ty*8
    const int tx = tid & 15;            // n = tx*4
    float acc[8][4];
    #pragma unroll
    for (int i = 0; i < 8; ++i)
        #pragma unroll
        for (int q = 0; q < 4; ++q) acc[i][q] = 0.f;

    for (int k0 = 0; k0 < 256; k0 += 16) {
        const float4 a0 = *(const float4*)(arow0 + k0);
        const float4 a1 = *(const float4*)(arow1 + k0);
        const float4 bv = *(const float4*)(bptr + (size_t)k0 * NC);
        __syncthreads();
        As[ak + 0][ar] = a0.x; As[ak + 1][ar] = a0.y; As[ak + 2][ar] = a0.z; As[ak + 3][ar] = a0.w;
        As[ak + 0][ar + 64] = a1.x; As[ak + 1][ar + 64] = a1.y; As[ak + 2][ar + 64] = a1.z; As[ak + 3][ar + 64] = a1.w;
        *(float4*)&Bs[bk][bn] = bv;
        __syncthreads();
        #pragma unroll
        for (int kk = 0; kk < 16; ++kk) {
            const float4 av0 = *(const float4*)&As[kk][ty * 8];
            const float4 av1 = *(const float4*)&As[kk][ty * 8 + 4];
            const float4 bv4 = *(const float4*)&Bs[kk][tx * 4];
            float a[8] = {av0.x, av0.y, av0.z, av0.w, av1.x, av1.y, av1.z, av1.w};
            float bb[4] = {bv4.x, bv4.y, bv4.z, bv4.w};
            #pragma unroll
            for (int i = 0; i < 8; ++i)
                #pragma unroll
                for (int q = 0; q < 4; ++q) acc[i][q] = fmaf(a[i], bb[q], acc[i][q]);
        }
    }
    const float4 bias = *(const float4*)(bihc + n0 + tx * 4);
    #pragma unroll
    for (int i = 0; i < 8; ++i) {
        const int r = m0 + ty * 8 + i;
        float4 o;
        o.x = acc[i][0] + bias.x; o.y = acc[i][1] + bias.y;
        o.z = acc[i][2] + bias.z; o.w = acc[i][3] + bias.w;
        *(float4*)(gi + (size_t)r * NC + n0 + tx * 4) = o;
    }
}

// ---------------------------------------------------------------------------
// K2: GRU recurrence. One block per (chain, batch-row). 512 threads:
//   j = tid&255 (hidden unit), half = tid>>8 (k-split of the 256-dim dot).
// h lives in LDS; whhT streamed from L2 each step (the expected bottleneck).
// ---------------------------------------------------------------------------
__global__ __launch_bounds__(512) void gru_kernel(
    const float* __restrict__ gi0, const float* __restrict__ gi1, const float* __restrict__ gi2,
    const float* __restrict__ whhT, const float* __restrict__ bhhc,
    float* __restrict__ e_src, float* __restrict__ e_tgt, float* __restrict__ e_cmnt,
    int chain_base)
{
    const int chain = chain_base + (int)(blockIdx.x >> 5);
    const int b = (int)(blockIdx.x & 31);
    const int seq = chain >> 1, dir = chain & 1;
    const int Tlen = (seq == 2) ? JJJ : TTT;
    const float* gi = (seq == 0) ? gi0 : (seq == 1) ? gi1 : gi2;
    float* e = (seq == 0) ? e_src : (seq == 1) ? e_tgt : e_cmnt;

    const int tid = threadIdx.x;
    const int j = tid & 255;
    const int half = tid >> 8;
    const int cb = dir * 768;

    __shared__ float h[256];
    __shared__ float parts[3][256];
    if (half == 0) h[j] = 0.f;
    const float br = bhhc[cb + j];
    const float bz = bhhc[cb + 256 + j];
    const float bn = bhhc[cb + 512 + j];
    const int kb = half * 128;
    const float* wbase = whhT + (size_t)kb * NC + cb + j;
    __syncthreads();

    for (int s = 0; s < Tlen; ++s) {
        const int t = dir ? (Tlen - 1 - s) : s;
        float ar = 0.f, az = 0.f, an = 0.f;
        const float* w = wbase;
        #pragma unroll 8
        for (int k = 0; k < 128; ++k) {
            const float hk = h[kb + k];
            ar = fmaf(w[0],   hk, ar);
            az = fmaf(w[256], hk, az);
            an = fmaf(w[512], hk, an);
            w += NC;
        }
        __syncthreads();                       // all lanes done reading h
        if (half == 1) { parts[0][j] = ar; parts[1][j] = az; parts[2][j] = an; }
        __syncthreads();
        if (half == 0) {
            const size_t row = (size_t)(b * Tlen + t);
            const float* girow = gi + row * NC + cb;
            const float gr_ = girow[j], gz_ = girow[256 + j], gn_ = girow[512 + j];
            const float sr = ar + parts[0][j] + br;
            const float sz = az + parts[1][j] + bz;
            const float sn = an + parts[2][j] + bn;
            const float r = 1.f / (1.f + __expf(-(gr_ + sr)));
            const float z = 1.f / (1.f + __expf(-(gz_ + sz)));
            const float n = tanhf(gn_ + r * sn);
            const float hnew = (1.f - z) * n + z * h[j];
            h[j] = hnew;
            e[row * 512 + (size_t)(dir * 256) + j] = hnew;
        }
        __syncthreads();                       // h updated before next step
    }
}

// ---------------------------------------------------------------------------
// K3: S[b,t,j] = sum_d (ctx[b,t,d]*w2[d]) * ec[b,j,d] + action[b,t]*w2[512]
// NT-GEMM per (seq,b): M=512(t) x N=128(j) x K=512. BM=BN=64, BK=16, 4x4 micro.
// ---------------------------------------------------------------------------
__global__ __launch_bounds__(256) void sim_gemm(
    const float* __restrict__ e_src, const float* __restrict__ e_tgt,
    const float* __restrict__ e_cmnt, const float* __restrict__ w2,
    const int* __restrict__ src_action, const int* __restrict__ tgt_action,
    float* __restrict__ S)
{
    const int seq = (int)(blockIdx.z >> 5);
    const int b = (int)(blockIdx.z & 31);
    const int t0 = blockIdx.x * 64;
    const int j0 = blockIdx.y * 64;
    const float* ctx = ((seq == 0) ? e_src : e_tgt) + (size_t)b * 512 * 512;
    const float* ec = e_cmnt + (size_t)b * 128 * 512;
    const int* act = (seq == 0) ? src_action : tgt_action;

    __shared__ __align__(16) float As[16][68];
    __shared__ __align__(16) float Bs[16][68];
    const int tid = threadIdx.x;
    const int lr = tid >> 2;            // 0..63
    const int lk = (tid & 3) << 2;      // 0,4,8,12
    const int ty = tid >> 4, tx = tid & 15;
    float acc[4][4];
    #pragma unroll
    for (int i = 0; i < 4; ++i)
        #pragma unroll
        for (int q = 0; q < 4; ++q) acc[i][q] = 0.f;

    for (int k0 = 0; k0 < 512; k0 += 16) {
        const float4 w4 = *(const float4*)(w2 + k0 + lk);
        const float4 a4 = *(const float4*)(ctx + (size_t)(t0 + lr) * 512 + k0 + lk);
        const float4 b4 = *(const float4*)(ec + (size_t)(j0 + lr) * 512 + k0 + lk);
        __syncthreads();
        As[lk + 0][lr] = a4.x * w4.x; As[lk + 1][lr] = a4.y * w4.y;
        As[lk + 2][lr] = a4.z * w4.z; As[lk + 3][lr] = a4.w * w4.w;
        Bs[lk + 0][lr] = b4.x; Bs[lk + 1][lr] = b4.y;
        Bs[lk + 2][lr] = b4.z; Bs[lk + 3][lr] = b4.w;
        __syncthreads();
        #pragma unroll
        for (int kk = 0; kk < 16; ++kk) {
            const float4 av = *(const float4*)&As[kk][ty * 4];
            const float4 bv = *(const float4*)&Bs[kk][tx * 4];
            float a[4] = {av.x, av.y, av.z, av.w};
            float bb[4] = {bv.x, bv.y, bv.z, bv.w};
            #pragma unroll
            for (int i = 0; i < 4; ++i)
                #pragma unroll
                for (int q = 0; q < 4; ++q) acc[i][q] = fmaf(a[i], bb[q], acc[i][q]);
        }
    }
    const float w2a = w2[512];
    #pragma unroll
    for (int i = 0; i < 4; ++i) {
        const int t = t0 + ty * 4 + i;
        const float aterm = (float)act[b * 512 + t] * w2a;
        float4 o;
        o.x = acc[i][0] + aterm; o.y = acc[i][1] + aterm;
        o.z = acc[i][2] + aterm; o.w = acc[i][3] + aterm;
        *(float4*)(S + ((size_t)((seq * 32 + b) * 512 + t)) * 128 + j0 + tx * 4) = o;
    }
}

// K4: rowmax over j (S rows are contiguous 128 floats)
__global__ __launch_bounds__(256) void rowmax_kernel(const float* __restrict__ S, float* __restrict__ rowmax)
{
    const int i = blockIdx.x * blockDim.x + threadIdx.x;   // seq*16384 + b*512 + t
    if (i >= 32768) return;
    const float* row = S + (size_t)i * 128;
    float m = row[0];
    for (int jj = 1; jj < 128; ++jj) m = fmaxf(m, row[jj]);
    rowmax[i] = m;
}

// K5: softmax over t (512) per (seq,b)
__global__ __launch_bounds__(256) void softmax_kernel(const float* __restrict__ rowmax, float* __restrict__ bw)
{
    const int base = blockIdx.x * 512;
    const int tid = threadIdx.x;
    __shared__ float red[256];
    const float v0 = rowmax[base + tid];
    const float v1 = rowmax[base + 256 + tid];
    red[tid] = fmaxf(v0, v1);
    __syncthreads();
    for (int off = 128; off > 0; off >>= 1) {
        if (tid < off) red[tid] = fmaxf(red[tid], red[tid + off]);
        __syncthreads();
    }
    const float M = red[0];
    __syncthreads();
    const float e0 = __expf(v0 - M), e1 = __expf(v1 - M);
    red[tid] = e0 + e1;
    __syncthreads();
    for (int off = 128; off > 0; off >>= 1) {
        if (tid < off) red[tid] += red[tid + off];
        __syncthreads();
    }
    const float inv = 1.f / red[0];
    bw[base + tid] = e0 * inv;
    bw[base + 256 + tid] = e1 * inv;
}

// K6: outS[seq,b,j] = sum_t bw[seq,b,t] * S[seq,b,t,j]
__global__ __launch_bounds__(256) void weighted_kernel(
    const float* __restrict__ S, const float* __restrict__ bw, float* __restrict__ outS)
{
    const int sb = blockIdx.x;          // seq*32 + b
    const int tid = threadIdx.x;
    const int j = tid & 127, half = tid >> 7;
    const float* Sb = S + (size_t)sb * 512 * 128;
    const float* w = bw + sb * 512;
    float acc = 0.f;
    for (int t = half * 256; t < half * 256 + 256; ++t)
        acc = fmaf(w[t], Sb[(size_t)t * 128 + j], acc);
    __shared__ float red[256];
    red[tid] = acc;
    __syncthreads();
    if (half == 0) outS[sb * 128 + j] = red[j] + red[128 + j];
}

// K7: write S_diff and result into d_out:  out[0..31]=result, out[32..8223]=S_diff
__global__ __launch_bounds__(256) void final_kernel(
    const float* __restrict__ outS, const float* __restrict__ rank_w,
    const float* __restrict__ rank_b, float* __restrict__ out)
{
    const int tid = threadIdx.x;
    for (int q = tid; q < 8192; q += 256) {
        const int b = q >> 8, c = q & 255;
        out[32 + q] = (c < 128) ? outS[b * 128 + c] : outS[4096 + b * 128 + (c - 128)];
    }
    if (tid < 32) {
        float acc = rank_b[0];
        for (int c = 0; c < 128; ++c) acc = fmaf(outS[tid * 128 + c], rank_w[c], acc);
        for (int c = 0; c < 128; ++c) acc = fmaf(outS[4096 + tid * 128 + c], rank_w[128 + c], acc);
        out[tid] = acc;
    }
}

// ---------------------------------------------------------------------------
extern "C" void kernel_launch(void* const* d_in, const int* in_sizes, int n_in,
                              void* d_out, int out_size, void* d_ws, size_t ws_size,
                              hipStream_t stream)
{
    const int* cmnt       = (const int*)d_in[0];
    const int* src_token  = (const int*)d_in[1];
    const int* tgt_token  = (const int*)d_in[2];
    const int* src_action = (const int*)d_in[3];
    const int* tgt_action = (const int*)d_in[4];
    const float* emb    = (const float*)d_in[5];
    const float* wih_f  = (const float*)d_in[6];
    const float* whh_f  = (const float*)d_in[7];
    const float* bih_f  = (const float*)d_in[8];
    const float* bhh_f  = (const float*)d_in[9];
    const float* wih_b  = (const float*)d_in[10];
    const float* whh_b  = (const float*)d_in[11];
    const float* bih_b  = (const float*)d_in[12];
    const float* bhh_b  = (const float*)d_in[13];
    const float* w2     = (const float*)d_in[14];
    const float* rank_w = (const float*)d_in[15];
    const float* rank_b = (const float*)d_in[16];
    float* out = (float*)d_out;

    float* ws = (float*)d_ws;
    size_t off = 0;
    int*   tok_all = (int*)(ws + off); off += 36864;
    float* wihT   = ws + off; off += 393216;
    float* whhT   = ws + off; off += 393216;
    float* bihc   = ws + off; off += 1536;
    float* bhhc   = ws + off; off += 1536;
    float* rowmax = ws + off; off += 32768;
    float* bw     = ws + off; off += 32768;
    float* outS   = ws + off; off += 8192;
    float* e_src  = ws + off; off += 8388608;
    float* e_tgt  = ws + off; off += 8388608;
    float* e_cmnt = ws + off; off += 2097152;
    float* S      = ws + off; off += 4194304;
    float* gi     = ws + off;
    const size_t avail = ws_size / 4 - off;
    const bool planP = avail >= 56623104ULL;   // gi for all 36864 rows at once

    hipLaunchKernelGGL(prep_kernel, dim3(512), dim3(256), 0, stream,
        cmnt, src_token, tgt_token, wih_f, wih_b, whh_f, whh_b,
        bih_f, bih_b, bhh_f, bhh_b, tok_all, wihT, whhT, bihc, bhhc);

    if (planP) {
        hipLaunchKernelGGL(gi_gemm, dim3(288, 24), dim3(256), 0, stream,
            tok_all, 36864, emb, wihT, bihc, gi);
        hipLaunchKernelGGL(gru_kernel, dim3(192), dim3(512), 0, stream,
            gi, gi + (size_t)16384 * NC, gi + (size_t)32768 * NC,
            whhT, bhhc, e_src, e_tgt, e_cmnt, 0);
    } else {
        // Serial fallback: reuse a single gi buffer per sequence
        hipLaunchKernelGGL(gi_gemm, dim3(128, 24), dim3(256), 0, stream,
            tok_all, 16384, emb, wihT, bihc, gi);
        hipLaunchKernelGGL(gru_kernel, dim3(64), dim3(512), 0, stream,
            gi, gi, gi, whhT, bhhc, e_src, e_tgt, e_cmnt, 0);
        hipLaunchKernelGGL(gi_gemm, dim3(128, 24), dim3(256), 0, stream,
            tok_all + 16384, 16384, emb, wihT, bihc, gi);
        hipLaunchKernelGGL(gru_kernel, dim3(64), dim3(512), 0, stream,
            gi, gi, gi, whhT, bhhc, e_src, e_tgt, e_cmnt, 2);
        hipLaunchKernelGGL(gi_gemm, dim3(32, 24), dim3(256), 0, stream,
            tok_all + 32768, 4096, emb, wihT, bihc, gi);
        hipLaunchKernelGGL(gru_kernel, dim3(64), dim3(512), 0, stream,
            gi, gi, gi, whhT, bhhc, e_src, e_tgt, e_cmnt, 4);
    }

    hipLaunchKernelGGL(sim_gemm, dim3(8, 2, 64), dim3(256), 0, stream,
        e_src, e_tgt, e_cmnt, w2, src_action, tgt_action, S);
    hipLaunchKernelGGL(rowmax_kernel, dim3(128), dim3(256), 0, stream, S, rowmax);
    hipLaunchKernelGGL(softmax_kernel, dim3(64), dim3(256), 0, stream, rowmax, bw);
    hipLaunchKernelGGL(weighted_kernel, dim3(64), dim3(256), 0, stream, S, bw, outS);
    hipLaunchKernelGGL(final_kernel, dim3(1), dim3(256), 0, stream, outS, rank_w, rank_b, out);
}